// Round 15
// baseline (8464.502 us; speedup 1.0000x reference)
//
#include <hip/hip_runtime.h>

typedef unsigned short u16;
typedef _Float16 f16;
typedef __attribute__((ext_vector_type(8))) _Float16 f16x8;
typedef __attribute__((ext_vector_type(8))) unsigned short u16x8;
typedef __attribute__((ext_vector_type(4))) float f32x4;
typedef __attribute__((ext_vector_type(4))) unsigned u32x4;

__device__ __forceinline__ unsigned split2(float v) {
  f16 h = (f16)v;
  f16 l2 = (f16)((v - (float)h) * 2048.0f);
  return (unsigned)__builtin_bit_cast(u16, h) | ((unsigned)__builtin_bit_cast(u16, l2) << 16);
}

__device__ __forceinline__ unsigned fld(const unsigned* p) {
  return __hip_atomic_load(p, __ATOMIC_RELAXED, __HIP_MEMORY_SCOPE_AGENT);
}

__global__ void k_zero(unsigned* __restrict__ z) {
  int i = blockIdx.x * blockDim.x + threadIdx.x;
  if (i < 32768) z[i] = 0u;
}

__global__ void k_wsplit(const float* __restrict__ wx, u16* __restrict__ th, u16* __restrict__ tl) {
  __shared__ float tile[32][33];
  int n0 = blockIdx.x * 32, k0 = blockIdx.y * 32;
  int tx = threadIdx.x, ty = threadIdx.y;
#pragma unroll
  for (int i = 0; i < 4; ++i)
    tile[ty + i * 8][tx] = wx[(size_t)(k0 + ty + i * 8) * 2048 + n0 + tx];
  __syncthreads();
#pragma unroll
  for (int i = 0; i < 4; ++i) {
    unsigned s = split2(tile[tx][ty + i * 8]);
    th[(size_t)(n0 + ty + i * 8) * 512 + k0 + tx] = (u16)s;
    tl[(size_t)(n0 + ty + i * 8) * 512 + k0 + tx] = (u16)(s >> 16);
  }
}

__global__ void k_pack(const float* __restrict__ W, u16* __restrict__ hi, u16* __restrict__ lo) {
  int idx = blockIdx.x * blockDim.x + threadIdx.x; // 131072
  int lane = idx & 63, kc = (idx >> 6) & 15, q = (idx >> 10) & 3, g = idx >> 12;
  int gcol = g * 16 + (lane & 15) + q * 512;
  int kb = kc * 32 + ((lane >> 4) << 3);
  u16x8 oh, ol;
#pragma unroll
  for (int j = 0; j < 8; ++j) {
    unsigned s = split2(W[(size_t)(kb + j) * 2048 + gcol]);
    oh[j] = (u16)s;
    ol[j] = (u16)(s >> 16);
  }
  *(u16x8*)(hi + (size_t)idx * 8) = oh;
  *(u16x8*)(lo + (size_t)idx * 8) = ol;
}

__global__ void __launch_bounds__(256, 1) k_gemm3(const float* __restrict__ A,
                                                  const u16* __restrict__ Bh, const u16* __restrict__ Bl,
                                                  float* __restrict__ C, int N, int K) {
  __shared__ u16 sA[2][128 * 64];
  __shared__ u16 sB[2][128 * 64];
  const int tid = threadIdx.x, l = tid & 63, w = tid >> 6;
  const int bx = blockIdx.x, by = blockIdx.y;
  const int wr = (w >> 1) * 64, wc = (w & 1) * 64;
  f32x4 acc0[4][4] = {}, acc1[4][4] = {};
  for (int k0 = 0; k0 < K; k0 += 64) {
#pragma unroll
    for (int s = 0; s < 4; ++s) {
      int cn = s * 256 + tid;
      int row = cn >> 3;
      int f0 = (cn & 7) * 8;
      int kb = f0 * 2;
      int sw = row * 128 + (kb ^ ((row & 7) << 4));
      const float* ap = A + ((size_t)(by * 128 + row) * K + k0 + f0);
      float4 a0 = *(const float4*)ap, a1 = *(const float4*)(ap + 4);
      float av[8] = {a0.x, a0.y, a0.z, a0.w, a1.x, a1.y, a1.z, a1.w};
      u16x8 ah_, al_;
#pragma unroll
      for (int j = 0; j < 8; ++j) {
        unsigned sp = split2(av[j]);
        ah_[j] = (u16)sp;
        al_[j] = (u16)(sp >> 16);
      }
      *(u16x8*)((char*)sA[0] + sw) = ah_;
      *(u16x8*)((char*)sA[1] + sw) = al_;
      size_t gb = (((size_t)(bx * 128 + row) * K + k0) << 1) + kb;
      *(u16x8*)((char*)sB[0] + sw) = *(const u16x8*)((const char*)Bh + gb);
      *(u16x8*)((char*)sB[1] + sw) = *(const u16x8*)((const char*)Bl + gb);
    }
    __syncthreads();
#pragma unroll
    for (int kc = 0; kc < 2; ++kc) {
      int kb = kc * 64 + (l >> 4) * 16;
      f16x8 ah[4], al[4], bh[4], bl[4];
#pragma unroll
      for (int mt = 0; mt < 4; ++mt) {
        int row = wr + mt * 16 + (l & 15);
        int off = row * 128 + (kb ^ ((row & 7) << 4));
        ah[mt] = *(const f16x8*)((const char*)sA[0] + off);
        al[mt] = *(const f16x8*)((const char*)sA[1] + off);
      }
#pragma unroll
      for (int nt = 0; nt < 4; ++nt) {
        int col = wc + nt * 16 + (l & 15);
        int off = col * 128 + (kb ^ ((col & 7) << 4));
        bh[nt] = *(const f16x8*)((const char*)sB[0] + off);
        bl[nt] = *(const f16x8*)((const char*)sB[1] + off);
      }
#pragma unroll
      for (int mt = 0; mt < 4; ++mt)
#pragma unroll
        for (int nt = 0; nt < 4; ++nt) {
          acc0[mt][nt] = __builtin_amdgcn_mfma_f32_16x16x32_f16(ah[mt], bh[nt], acc0[mt][nt], 0, 0, 0);
          acc1[mt][nt] = __builtin_amdgcn_mfma_f32_16x16x32_f16(ah[mt], bl[nt], acc1[mt][nt], 0, 0, 0);
          acc1[mt][nt] = __builtin_amdgcn_mfma_f32_16x16x32_f16(al[mt], bh[nt], acc1[mt][nt], 0, 0, 0);
        }
    }
    __syncthreads();
  }
#pragma unroll
  for (int mt = 0; mt < 4; ++mt)
#pragma unroll
    for (int nt = 0; nt < 4; ++nt)
#pragma unroll
      for (int j = 0; j < 4; ++j) {
        int row = by * 128 + wr + mt * 16 + ((l >> 4) << 2) + j;
        int col = bx * 128 + wc + nt * 16 + (l & 15);
        C[(size_t)row * N + col] = acc0[mt][nt][j] + acc1[mt][nt][j] * (1.0f / 2048.0f);
      }
}

__global__ void __launch_bounds__(256) k_ln2(float* __restrict__ X, const float* __restrict__ g,
                                             const float* __restrict__ b, const float* __restrict__ bias) {
  const int row = blockIdx.x, tid = threadIdx.x;
  float* rp = X + (size_t)row * 2048 + tid * 8;
  float4 v0 = *(const float4*)rp, v1 = *(const float4*)(rp + 4);
  float x[8] = {v0.x, v0.y, v0.z, v0.w, v1.x, v1.y, v1.z, v1.w};
  float s1 = 0.f, s2 = 0.f;
#pragma unroll
  for (int j = 0; j < 8; ++j) { s1 += x[j]; s2 += x[j] * x[j]; }
#pragma unroll
  for (int m = 1; m <= 32; m <<= 1) { s1 += __shfl_xor(s1, m, 64); s2 += __shfl_xor(s2, m, 64); }
  __shared__ float a1[4], a2[4];
  if ((tid & 63) == 0) { a1[tid >> 6] = s1; a2[tid >> 6] = s2; }
  __syncthreads();
  s1 = a1[0] + a1[1] + a1[2] + a1[3];
  s2 = a2[0] + a2[1] + a2[2] + a2[3];
  float mu = s1 * (1.f / 2048.f);
  float var = s2 * (1.f / 2048.f) - mu * mu;
  float rstd = 1.0f / sqrtf(var + 1e-5f);
#pragma unroll
  for (int j = 0; j < 8; ++j) {
    int c = tid * 8 + j;
    x[j] = (x[j] - mu) * rstd * g[c] + b[c] + bias[c];
  }
  *(float4*)rp = {x[0], x[1], x[2], x[3]};
  *(float4*)(rp + 4) = {x[4], x[5], x[6], x[7]};
}

__device__ __forceinline__ void unpk(uint4 a, uint4 b, f16x8& hi, f16x8& lo) {
  u32x4 H, L;
  H[0] = __builtin_amdgcn_perm(a.y, a.x, 0x05040100u);
  H[1] = __builtin_amdgcn_perm(a.w, a.z, 0x05040100u);
  H[2] = __builtin_amdgcn_perm(b.y, b.x, 0x05040100u);
  H[3] = __builtin_amdgcn_perm(b.w, b.z, 0x05040100u);
  L[0] = __builtin_amdgcn_perm(a.y, a.x, 0x07060302u);
  L[1] = __builtin_amdgcn_perm(a.w, a.z, 0x07060302u);
  L[2] = __builtin_amdgcn_perm(b.y, b.x, 0x07060302u);
  L[3] = __builtin_amdgcn_perm(b.w, b.z, 0x07060302u);
  hi = __builtin_bit_cast(f16x8, H);
  lo = __builtin_bit_cast(f16x8, L);
}

// ---- dual-domain layer-pipelined scan (one 128-step chunk, 129 rounds) ----
__global__ void __launch_bounds__(256, 1) k_scan9(
    const float* __restrict__ xn, const u16* __restrict__ frg,
    const float* __restrict__ gx, const float* __restrict__ bx,
    const float* __restrict__ gh, const float* __restrict__ bh,
    const float* __restrict__ bias,
    const float* __restrict__ h0, const float* __restrict__ c0,
    unsigned* __restrict__ hp0, unsigned* __restrict__ hp1,
    unsigned long long* __restrict__ pt0, unsigned long long* __restrict__ pt1,
    unsigned* __restrict__ f0, unsigned* __restrict__ f1,
    float* __restrict__ cs0, float* __restrict__ cs1,
    float* __restrict__ out, int t0, int first) {
  __shared__ u16 pk[32768];
  __shared__ u16 sb[32768];
  __shared__ float musd[256];
  const int tid = threadIdx.x;
  const int l = tid & 63, w = tid >> 6;
  const int g = blockIdx.x;
  const int layer = g >> 5, gg = g & 31;
  const int lq = l >> 4, ll = l & 15;
  const int hcol = gg * 16 + ll;
  const bool L0 = (layer == 0);
  unsigned* fown = L0 ? f0 : f1;
  unsigned* foth = L0 ? f1 : f0;

  const u16* pkG = frg + (size_t)(L0 ? 0 : 2) * 1048576 + (size_t)gg * 32768;
  const u16* sbG = frg + (size_t)(L0 ? 1 : 4) * 1048576 + (size_t)gg * 32768;
  const u16* whlG = frg + (size_t)3 * 1048576 + (size_t)gg * 32768;
  const u16* wxlG = frg + (size_t)5 * 1048576 + (size_t)gg * 32768;
  for (int c = tid; c < 4096; c += 256) {
    *(u16x8*)(pk + (size_t)c * 8) = *(const u16x8*)(pkG + (size_t)c * 8);
    *(u16x8*)(sb + (size_t)c * 8) = *(const u16x8*)(sbG + (size_t)c * 8);
  }
  float gxv[4], bxv[4], ghv[4], bhv[4], biv[4];
#pragma unroll
  for (int q = 0; q < 4; ++q) {
    int gc = layer * 2048 + hcol + q * 512;
    gxv[q] = gx[gc]; bxv[q] = bx[gc]; ghv[q] = gh[gc]; bhv[q] = bh[gc]; biv[q] = bias[gc];
  }
  float cr[4];
  {
    const float* cl = first ? (c0 + (size_t)layer * 32768) : (L0 ? cs0 : cs1);
#pragma unroll
    for (int j = 0; j < 4; ++j)
      cr[j] = cl[(w * 16 + lq * 4 + j) * 512 + hcol];
  }
  if (first) {
    unsigned* dst = L0 ? (hp0 + 32768) : hp1;
    for (int u = tid; u < 1024; u += 256) {
      int row = 2 * gg + (u >> 9), col = u & 511;
      __hip_atomic_store(&dst[row * 512 + col],
                         split2(h0[(size_t)layer * 32768 + row * 512 + col]),
                         __ATOMIC_RELAXED, __HIP_MEMORY_SCOPE_AGENT);
    }
  }
  unsigned bid = 0;
#define BAR_ARRIVE()                                                                         \
  do {                                                                                       \
    bid++;                                                                                   \
    asm volatile("s_waitcnt vmcnt(0)" ::: "memory");                                         \
    __syncthreads();                                                                         \
    if (tid == 0)                                                                            \
      __hip_atomic_store(&fown[gg * 32], bid, __ATOMIC_RELAXED, __HIP_MEMORY_SCOPE_AGENT);   \
  } while (0)
#define BAR_WAIT(XEN, XTHR)                                                                  \
  do {                                                                                       \
    if (tid < 32) {                                                                          \
      while (fld(&fown[tid * 32]) < bid) {}                                                  \
    } else if (tid < 64 && (XEN)) {                                                          \
      unsigned xt_ = (XTHR);                                                                 \
      while (fld(&foth[(tid - 32) * 32]) < xt_) {}                                           \
    }                                                                                        \
    __builtin_amdgcn_fence(__ATOMIC_ACQUIRE, "agent");                                       \
  } while (0)

  float xp[16];
  BAR_ARRIVE();
  if (L0) {
#pragma unroll
    for (int q = 0; q < 4; ++q)
#pragma unroll
      for (int j = 0; j < 4; ++j)
        xp[q * 4 + j] = xn[(size_t)(w * 16 + lq * 4 + j) * 2048 + hcol + q * 512];
  }
  BAR_WAIT(false, 0u);
  __syncthreads();

  for (int r = 0; r < 129; ++r) {
    const bool act = L0 ? (r < 128) : (r >= 1);
    const int tl = L0 ? r : r - 1;
    const int t_abs = t0 + tl;
    const int p = t_abs & 1;
    float yx[4][4], yh[4][4];
    if (act) {
      if (L0) {
        const unsigned* hb = hp0 + (size_t)(p ^ 1) * 32768;
        f32x4 a0[4] = {}, a1[4] = {};
#pragma unroll
        for (int kc = 0; kc < 16; ++kc) {
          const unsigned* hpx = hb + ((size_t)(w * 16 + ll) * 512 + kc * 32 + lq * 8);
          f16x8 ah, al;
          unpk(*(const uint4*)hpx, *(const uint4*)(hpx + 4), ah, al);
#pragma unroll
          for (int q = 0; q < 4; ++q) {
            size_t fo = ((size_t)(q * 16 + kc) * 64 + l) * 8;
            f16x8 bhv_ = *(const f16x8*)(pk + fo);
            f16x8 blv_ = *(const f16x8*)(sb + fo);
            a0[q] = __builtin_amdgcn_mfma_f32_16x16x32_f16(ah, bhv_, a0[q], 0, 0, 0);
            a1[q] = __builtin_amdgcn_mfma_f32_16x16x32_f16(ah, blv_, a1[q], 0, 0, 0);
            a1[q] = __builtin_amdgcn_mfma_f32_16x16x32_f16(al, bhv_, a1[q], 0, 0, 0);
          }
        }
#pragma unroll
        for (int q = 0; q < 4; ++q)
#pragma unroll
          for (int j = 0; j < 4; ++j)
            yh[q][j] = a0[q][j] + a1[q][j] * (1.0f / 2048.0f);
      } else {
        const unsigned* xb = hp0 + (size_t)p * 32768;
        f32x4 ax0[4] = {}, ax1[4] = {}, ah0[4] = {}, ah1[4] = {};
#pragma unroll
        for (int kc = 0; kc < 16; ++kc) {
          size_t aoff = (size_t)(w * 16 + ll) * 512 + kc * 32 + lq * 8;
          f16x8 xah, xal, hah, hal;
          unpk(*(const uint4*)(xb + aoff), *(const uint4*)(xb + aoff + 4), xah, xal);
          unpk(*(const uint4*)(hp1 + aoff), *(const uint4*)(hp1 + aoff + 4), hah, hal);
#pragma unroll
          for (int q = 0; q < 4; ++q) {
            size_t fo = ((size_t)(q * 16 + kc) * 64 + l) * 8;
            f16x8 whh_ = *(const f16x8*)(pk + fo);
            f16x8 wxh_ = *(const f16x8*)(sb + fo);
            f16x8 whl_ = *(const f16x8*)(whlG + fo);
            f16x8 wxl_ = *(const f16x8*)(wxlG + fo);
            ax0[q] = __builtin_amdgcn_mfma_f32_16x16x32_f16(xah, wxh_, ax0[q], 0, 0, 0);
            ax1[q] = __builtin_amdgcn_mfma_f32_16x16x32_f16(xah, wxl_, ax1[q], 0, 0, 0);
            ax1[q] = __builtin_amdgcn_mfma_f32_16x16x32_f16(xal, wxh_, ax1[q], 0, 0, 0);
            ah0[q] = __builtin_amdgcn_mfma_f32_16x16x32_f16(hah, whh_, ah0[q], 0, 0, 0);
            ah1[q] = __builtin_amdgcn_mfma_f32_16x16x32_f16(hah, whl_, ah1[q], 0, 0, 0);
            ah1[q] = __builtin_amdgcn_mfma_f32_16x16x32_f16(hal, whh_, ah1[q], 0, 0, 0);
          }
        }
#pragma unroll
        for (int q = 0; q < 4; ++q)
#pragma unroll
          for (int j = 0; j < 4; ++j) {
            yx[q][j] = ax0[q][j] + ax1[q][j] * (1.0f / 2048.0f);
            yh[q][j] = ah0[q][j] + ah1[q][j] * (1.0f / 2048.0f);
          }
      }
      float s1h[4], s2h[4], s1x[4], s2x[4];
#pragma unroll
      for (int j = 0; j < 4; ++j) {
        s1h[j] = yh[0][j] + yh[1][j] + yh[2][j] + yh[3][j];
        s2h[j] = yh[0][j] * yh[0][j] + yh[1][j] * yh[1][j] + yh[2][j] * yh[2][j] + yh[3][j] * yh[3][j];
        if (!L0) {
          s1x[j] = yx[0][j] + yx[1][j] + yx[2][j] + yx[3][j];
          s2x[j] = yx[0][j] * yx[0][j] + yx[1][j] * yx[1][j] + yx[2][j] * yx[2][j] + yx[3][j] * yx[3][j];
        }
      }
#pragma unroll
      for (int m = 1; m <= 8; m <<= 1)
#pragma unroll
        for (int j = 0; j < 4; ++j) {
          s1h[j] += __shfl_xor(s1h[j], m, 64);
          s2h[j] += __shfl_xor(s2h[j], m, 64);
          if (!L0) {
            s1x[j] += __shfl_xor(s1x[j], m, 64);
            s2x[j] += __shfl_xor(s2x[j], m, 64);
          }
        }
      if (ll == 0) {
#pragma unroll
        for (int j = 0; j < 4; ++j) {
          int rr = w * 16 + lq * 4 + j;
          unsigned long long vh = ((unsigned long long)__builtin_bit_cast(unsigned, s2h[j]) << 32) |
                                  (unsigned long long)__builtin_bit_cast(unsigned, s1h[j]);
          if (L0) {
            __hip_atomic_store(&pt0[(size_t)p * 2048 + (size_t)rr * 32 + gg], vh,
                               __ATOMIC_RELAXED, __HIP_MEMORY_SCOPE_AGENT);
          } else {
            unsigned long long vx = ((unsigned long long)__builtin_bit_cast(unsigned, s2x[j]) << 32) |
                                    (unsigned long long)__builtin_bit_cast(unsigned, s1x[j]);
            __hip_atomic_store(&pt1[((size_t)(p * 2 + 0) * 64 + rr) * 32 + gg], vx,
                               __ATOMIC_RELAXED, __HIP_MEMORY_SCOPE_AGENT);
            __hip_atomic_store(&pt1[((size_t)(p * 2 + 1) * 64 + rr) * 32 + gg], vh,
                               __ATOMIC_RELAXED, __HIP_MEMORY_SCOPE_AGENT);
          }
        }
      }
    }
    BAR_ARRIVE();
    BAR_WAIT(L0 && r >= 2, bid - 2);
    float hs[4];
    if (act) {
      if (tid < 64) {
        if (L0) {
          const uint4* pp = (const uint4*)(pt0 + (size_t)p * 2048 + (size_t)tid * 32);
          float a1 = 0.f, a2 = 0.f;
#pragma unroll
          for (int i = 0; i < 16; ++i) {
            uint4 v = pp[i];
            a1 += __builtin_bit_cast(float, v.x); a2 += __builtin_bit_cast(float, v.y);
            a1 += __builtin_bit_cast(float, v.z); a2 += __builtin_bit_cast(float, v.w);
          }
          float mu = a1 * (1.f / 2048.f), ex2 = a2 * (1.f / 2048.f);
          musd[tid] = mu;
          musd[64 + tid] = 1.0f / sqrtf(ex2 - mu * mu + 1e-5f);
        } else {
          const uint4* px = (const uint4*)(pt1 + ((size_t)(p * 2 + 0) * 64 + tid) * 32);
          const uint4* ph = (const uint4*)(pt1 + ((size_t)(p * 2 + 1) * 64 + tid) * 32);
          float a1x = 0.f, a2x = 0.f, a1h = 0.f, a2h = 0.f;
#pragma unroll
          for (int i = 0; i < 16; ++i) {
            uint4 vx = px[i], vh = ph[i];
            a1x += __builtin_bit_cast(float, vx.x); a2x += __builtin_bit_cast(float, vx.y);
            a1x += __builtin_bit_cast(float, vx.z); a2x += __builtin_bit_cast(float, vx.w);
            a1h += __builtin_bit_cast(float, vh.x); a2h += __builtin_bit_cast(float, vh.y);
            a1h += __builtin_bit_cast(float, vh.z); a2h += __builtin_bit_cast(float, vh.w);
          }
          float mux = a1x * (1.f / 2048.f), ex2x = a2x * (1.f / 2048.f);
          float muh = a1h * (1.f / 2048.f), ex2h = a2h * (1.f / 2048.f);
          musd[tid] = mux;
          musd[64 + tid] = 1.0f / sqrtf(ex2x - mux * mux + 1e-5f);
          musd[128 + tid] = muh;
          musd[192 + tid] = 1.0f / sqrtf(ex2h - muh * muh + 1e-5f);
        }
      }
      __syncthreads();
#pragma unroll
      for (int j = 0; j < 4; ++j) {
        int rr = w * 16 + lq * 4 + j;
        float gv[4];
        if (L0) {
          float mu = musd[rr], rstd = musd[64 + rr];
#pragma unroll
          for (int q = 0; q < 4; ++q)
            gv[q] = (yh[q][j] - mu) * rstd * ghv[q] + bhv[q] + xp[q * 4 + j];
        } else {
          float mux = musd[rr], rsx = musd[64 + rr];
          float muh = musd[128 + rr], rsh = musd[192 + rr];
#pragma unroll
          for (int q = 0; q < 4; ++q)
            gv[q] = (yx[q][j] - mux) * rsx * gxv[q] + bxv[q] + biv[q] +
                    (yh[q][j] - muh) * rsh * ghv[q] + bhv[q];
        }
        float fi = 1.f / (1.f + expf(-gv[0]));
        float ff = 1.f / (1.f + expf(-gv[1]));
        float fo = 1.f / (1.f + expf(-gv[2]));
        float fu = tanhf(gv[3]);
        cr[j] = ff * cr[j] + fi * fu;
        float h = fo * tanhf(cr[j]);
        hs[j] = h;
        size_t ro = (size_t)rr * 512 + hcol;
        unsigned* dst = L0 ? (hp0 + (size_t)p * 32768) : hp1;
        __hip_atomic_store(&dst[ro], split2(h), __ATOMIC_RELAXED, __HIP_MEMORY_SCOPE_AGENT);
      }
    }
    BAR_ARRIVE();
    if (act) {
#pragma unroll
      for (int j = 0; j < 4; ++j) {
        int rr = w * 16 + lq * 4 + j;
        size_t ro = (size_t)rr * 512 + hcol;
        if (!L0)
          __hip_atomic_store(&out[(size_t)t_abs * 32768 + ro], hs[j],
                             __ATOMIC_RELAXED, __HIP_MEMORY_SCOPE_AGENT);
        if (tl == 127)
          __hip_atomic_store(&(L0 ? cs0 : cs1)[ro], cr[j],
                             __ATOMIC_RELAXED, __HIP_MEMORY_SCOPE_AGENT);
        if (t_abs == 255) {
          __hip_atomic_store(&out[8388608 + (size_t)layer * 32768 + ro], hs[j],
                             __ATOMIC_RELAXED, __HIP_MEMORY_SCOPE_AGENT);
          __hip_atomic_store(&out[8388608 + 65536 + (size_t)layer * 32768 + ro], cr[j],
                             __ATOMIC_RELAXED, __HIP_MEMORY_SCOPE_AGENT);
        }
      }
    }
    if (L0 && r < 127) {
      const float* xrow = xn + (size_t)(r + 1) * 64 * 2048;
#pragma unroll
      for (int q = 0; q < 4; ++q)
#pragma unroll
        for (int j = 0; j < 4; ++j)
          xp[q * 4 + j] = xrow[(size_t)(w * 16 + lq * 4 + j) * 2048 + hcol + q * 512];
    }
    BAR_WAIT(!L0, bid);
    __syncthreads();
  }
#undef BAR_ARRIVE
#undef BAR_WAIT
}

// ---- workspace layout (bytes), max ~84.7 MB (proven-safe: R0 ran at 88.1 MB) ----
#define XN_OFF  0ull
#define WXH_OFF 67108864ull
#define WXL_OFF 69206016ull
#define FRG_OFF 71303168ull
#define HP0_OFF 83886080ull
#define HP1_OFF 84148224ull
#define CS0_OFF 84279296ull
#define CS1_OFF 84410368ull
#define PT0_OFF 84541440ull
#define PT1_OFF 84574208ull
#define FLG_OFF 84639744ull

extern "C" void kernel_launch(void* const* d_in, const int* in_sizes, int n_in,
                              void* d_out, int out_size, void* d_ws, size_t ws_size,
                              hipStream_t stream) {
  const float* inputs = (const float*)d_in[0];
  const float* h0 = (const float*)d_in[1];
  const float* c0 = (const float*)d_in[2];
  const float* wx = (const float*)d_in[3];
  const float* wh = (const float*)d_in[4];
  const float* bias = (const float*)d_in[5];
  const float* gxp = (const float*)d_in[6];
  const float* bxp = (const float*)d_in[7];
  const float* ghp = (const float*)d_in[8];
  const float* bhp = (const float*)d_in[9];
  float* out = (float*)d_out;
  char* ws = (char*)d_ws;

  float* xn = (float*)(ws + XN_OFF);
  u16* wxh = (u16*)(ws + WXH_OFF);
  u16* wxl = (u16*)(ws + WXL_OFF);
  u16* frg = (u16*)(ws + FRG_OFF);
  unsigned* hp0 = (unsigned*)(ws + HP0_OFF);
  unsigned* hp1 = (unsigned*)(ws + HP1_OFF);
  float* cs0 = (float*)(ws + CS0_OFF);
  float* cs1 = (float*)(ws + CS1_OFF);
  unsigned long long* pt0 = (unsigned long long*)(ws + PT0_OFF);
  unsigned long long* pt1 = (unsigned long long*)(ws + PT1_OFF);
  unsigned* flg = (unsigned*)(ws + FLG_OFF);

  k_zero<<<128, 256, 0, stream>>>((unsigned*)(ws + PT0_OFF));
  k_wsplit<<<dim3(64, 16), dim3(32, 8), 0, stream>>>(wx, wxh, wxl);
  k_pack<<<512, 256, 0, stream>>>(wh, frg + (size_t)0 * 1048576, frg + (size_t)1 * 1048576);
  k_pack<<<512, 256, 0, stream>>>(wh + 1048576, frg + (size_t)2 * 1048576, frg + (size_t)3 * 1048576);
  k_pack<<<512, 256, 0, stream>>>(wx + 1048576, frg + (size_t)4 * 1048576, frg + (size_t)5 * 1048576);

  for (int k = 0; k < 2; ++k) {
    k_gemm3<<<dim3(16, 64), 256, 0, stream>>>(inputs + (size_t)k * 8192 * 512, wxh, wxl,
                                              xn, 2048, 512);
    k_ln2<<<8192, 256, 0, stream>>>(xn, gxp, bxp, bias);
    k_scan9<<<64, 256, 0, stream>>>(xn, frg, gxp, bxp, ghp, bhp, bias, h0, c0,
                                    hp0, hp1, pt0, pt1,
                                    flg + (size_t)(k * 2 + 0) * 2048,
                                    flg + (size_t)(k * 2 + 1) * 2048,
                                    cs0, cs1, out, k * 128, (k == 0) ? 1 : 0);
  }
}